// Round 3
// baseline (3605.978 us; speedup 1.0000x reference)
//
#include <hip/hip_runtime.h>

#define HID   256
#define BATCH 2048
#define NGATE 1024
#define BM    16        // batch rows per workgroup
#define NWG   128       // BATCH/BM -> one WG per CU on 128 CUs
#define TPB   1024      // 16 waves
#define LDS_BYTES 163840  // 16KB h double-buffer + 144KB weight cache (full LDS)

typedef __attribute__((ext_vector_type(8))) short bf16x8;
typedef __attribute__((ext_vector_type(4))) float f32x4;

__device__ __forceinline__ unsigned short f2bf(float x){
  unsigned int u = __builtin_bit_cast(unsigned int, x);
  u += 0x7fffu + ((u >> 16) & 1u);          // RNE
  return (unsigned short)(u >> 16);
}
__device__ __forceinline__ float fsigm(float x){
  return __builtin_amdgcn_rcpf(1.0f + __expf(-x));
}
__device__ __forceinline__ float ftanh_(float x){
  return fmaf(2.0f, __builtin_amdgcn_rcpf(1.0f + __expf(-2.0f*x)), -1.0f);
}

// lgkmcnt-only barrier: orders the LDS hnext writes/reads without draining
// the global output stores (vmcnt) every step.
#define STEP_BARRIER() do {                                   \
    __builtin_amdgcn_sched_barrier(0);                        \
    asm volatile("s_waitcnt lgkmcnt(0)" ::: "memory");        \
    __builtin_amdgcn_s_barrier();                             \
    __builtin_amdgcn_sched_barrier(0);                        \
  } while (0)

// Pack W_ih and (W_ih+W_hh) into MFMA B-fragment order:
// frag(nt,kt) is 1024B, lane-linear: lane l holds W[nt*16 + (l&15)][kt*32 + (l>>4)*8 + j]
__global__ void pack_kernel(const float* __restrict__ Wih, const float* __restrict__ Whh,
                            const float* __restrict__ bih, const float* __restrict__ bhh,
                            unsigned short* __restrict__ Wih_p,
                            unsigned short* __restrict__ Wsum_p,
                            float* __restrict__ bias){
  int tid = blockIdx.x * blockDim.x + threadIdx.x;   // 0..262143
  int j  = tid & 7;
  int ln = (tid >> 3) & 63;
  int kt = (tid >> 9) & 7;
  int nt = tid >> 12;
  int n = nt*16 + (ln & 15);
  int k = kt*32 + (ln >> 4)*8 + j;
  float wih = Wih[n*HID + k];
  float whh = Whh[n*HID + k];
  Wih_p[tid]  = f2bf(wih);
  Wsum_p[tid] = f2bf(wih + whh);
  if (tid < NGATE) bias[tid] = bih[tid] + bhh[tid];
}

// One LSTM time step. Wave w owns hidden units [16w,16w+16) for all 4 gates.
// Per-wave B-fragments (32 total = 4 gates x 8 kt):
//   kt 0-3 all gates      -> 16 frags pinned in VGPRs (asm-opaque)
//   kt 4-5 all gates + kt6 ga0 -> 9 frags in LDS (loaded once)
//   kt6 ga1-3, kt7 ga0-3  -> 7 frags streamed from L2 each step
template<bool FIRST>
__device__ __forceinline__ void lstm_step(
    int t, int T, int g, int w, int l, int l15, int lq,
    const unsigned short* __restrict__ hcur,   // LDS, A-frag layout, 4096 ushorts
    unsigned short* __restrict__ hnext,        // LDS
    const unsigned short* __restrict__ wl,     // LDS weight cache base
    const bf16x8 (&wregs)[4][4],               // [kt][ga]
    const unsigned short* __restrict__ Wih_p,
    const unsigned short* __restrict__ Wsum_p,
    const float (&bv)[4], float (&cs)[4],
    float* __restrict__ out)
{
  // bias folded into accumulator init (C-element cols all equal this lane's unit)
  f32x4 acc[4];
  #pragma unroll
  for (int ga = 0; ga < 4; ++ga){
    acc[ga][0] = bv[ga]; acc[ga][1] = bv[ga]; acc[ga][2] = bv[ga]; acc[ga][3] = bv[ga];
  }

  if constexpr (FIRST){
    // t==0 uses W_ih: stream all 8 k-tiles (one-time)
    #pragma unroll
    for (int kt = 0; kt < 8; ++kt){
      bf16x8 av = *(const bf16x8*)&hcur[kt*512 + l*8];
      #pragma unroll
      for (int ga = 0; ga < 4; ++ga){
        bf16x8 bfr = *(const bf16x8*)(Wih_p + (size_t)((ga*16 + w)*8 + kt)*512 + l*8);
        acc[ga] = __builtin_amdgcn_mfma_f32_16x16x32_bf16(av, bfr, acc[ga], 0, 0, 0);
      }
    }
  } else {
    // Batch A: kt6 ga1-3 + kt7 ga0 (4 frags, 16 VGPRs in flight), issued first.
    bf16x8 bsA[4];
    bsA[0] = *(const bf16x8*)(Wsum_p + (size_t)((1*16 + w)*8 + 6)*512 + l*8);
    bsA[1] = *(const bf16x8*)(Wsum_p + (size_t)((2*16 + w)*8 + 6)*512 + l*8);
    bsA[2] = *(const bf16x8*)(Wsum_p + (size_t)((3*16 + w)*8 + 6)*512 + l*8);
    bsA[3] = *(const bf16x8*)(Wsum_p + (size_t)((0*16 + w)*8 + 7)*512 + l*8);
    __builtin_amdgcn_sched_barrier(0);

    // kt 0-3: pinned register weights (16 MFMAs, no memory dependence on B)
    #pragma unroll
    for (int kc = 0; kc < 4; ++kc){
      bf16x8 av = *(const bf16x8*)&hcur[kc*512 + l*8];
      #pragma unroll
      for (int ga = 0; ga < 4; ++ga)
        acc[ga] = __builtin_amdgcn_mfma_f32_16x16x32_bf16(av, wregs[kc][ga], acc[ga], 0, 0, 0);
    }

    // Batch B: kt7 ga1-3 (3 frags)
    bf16x8 bsB[3];
    bsB[0] = *(const bf16x8*)(Wsum_p + (size_t)((1*16 + w)*8 + 7)*512 + l*8);
    bsB[1] = *(const bf16x8*)(Wsum_p + (size_t)((2*16 + w)*8 + 7)*512 + l*8);
    bsB[2] = *(const bf16x8*)(Wsum_p + (size_t)((3*16 + w)*8 + 7)*512 + l*8);
    __builtin_amdgcn_sched_barrier(0);

    // kt 4-5: LDS-cached weights (idx 0-7)
    #pragma unroll
    for (int kc = 0; kc < 2; ++kc){
      bf16x8 av = *(const bf16x8*)&hcur[(4+kc)*512 + l*8];
      #pragma unroll
      for (int ga = 0; ga < 4; ++ga){
        bf16x8 bfr = *(const bf16x8*)&wl[((w*9) + kc*4 + ga)*512 + l*8];
        acc[ga] = __builtin_amdgcn_mfma_f32_16x16x32_bf16(av, bfr, acc[ga], 0, 0, 0);
      }
    }

    // kt 6: ga0 from LDS (idx 8), ga1-3 from batch A
    {
      bf16x8 av = *(const bf16x8*)&hcur[6*512 + l*8];
      bf16x8 b0 = *(const bf16x8*)&wl[((w*9) + 8)*512 + l*8];
      acc[0] = __builtin_amdgcn_mfma_f32_16x16x32_bf16(av, b0,     acc[0], 0, 0, 0);
      acc[1] = __builtin_amdgcn_mfma_f32_16x16x32_bf16(av, bsA[0], acc[1], 0, 0, 0);
      acc[2] = __builtin_amdgcn_mfma_f32_16x16x32_bf16(av, bsA[1], acc[2], 0, 0, 0);
      acc[3] = __builtin_amdgcn_mfma_f32_16x16x32_bf16(av, bsA[2], acc[3], 0, 0, 0);
    }
    // kt 7: ga0 from batch A, ga1-3 from batch B
    {
      bf16x8 av = *(const bf16x8*)&hcur[7*512 + l*8];
      acc[0] = __builtin_amdgcn_mfma_f32_16x16x32_bf16(av, bsA[3], acc[0], 0, 0, 0);
      acc[1] = __builtin_amdgcn_mfma_f32_16x16x32_bf16(av, bsB[0], acc[1], 0, 0, 0);
      acc[2] = __builtin_amdgcn_mfma_f32_16x16x32_bf16(av, bsB[1], acc[2], 0, 0, 0);
      acc[3] = __builtin_amdgcn_mfma_f32_16x16x32_bf16(av, bsB[2], acc[3], 0, 0, 0);
    }
  }

  // Epilogue: C layout col = l&15 (unit), row = lq*4 + r. All 4 gates in-lane.
  const int u   = w*16 + l15;
  const int ktu = w >> 1;
  const int kgu = ((w & 1) << 1) | (l15 >> 3);
  const int ju  = l15 & 7;
  const int orow = FIRST ? 0 : (T - t);        // x_hat[0]=h_0, x_hat[T-t]=h_t
  float* __restrict__ orp = out + (size_t)orow * (BATCH*HID);
  const bool last = (t == T - 1);

  #pragma unroll
  for (int r = 0; r < 4; ++r){
    const int m = lq*4 + r;
    const float iv = fsigm (acc[0][r]);
    const float fv = fsigm (acc[1][r]);
    const float gv = ftanh_(acc[2][r]);
    const float ov = fsigm (acc[3][r]);
    const float cn = fv * cs[r] + iv * gv;
    cs[r] = cn;
    const float hv = ov * ftanh_(cn);
    // next step's A-frag element (row m, k = u)
    hnext[ktu*512 + (kgu*16 + m)*8 + ju] = f2bf(hv);
    const size_t gi = (size_t)(g*BM + m)*HID + u;
    orp[gi] = hv;
    if (last){
      out[(size_t)T*(BATCH*HID) + gi]       = hv;   // hf
      out[(size_t)(T + 1)*(BATCH*HID) + gi] = cn;   // cf
    }
  }
}

__global__ __launch_bounds__(TPB, 4)
void lstm_kernel(const float* __restrict__ h_in,
                 const unsigned short* __restrict__ Wih_p,
                 const unsigned short* __restrict__ Wsum_p,
                 const float* __restrict__ bias,
                 const int* __restrict__ seqlen,
                 float* __restrict__ out){
  extern __shared__ unsigned short lds[];
  unsigned short* hb = lds;           // [2][4096] h in A-frag layout (double buffer)
  unsigned short* wl = lds + 8192;    // [16 waves][9 frags][512] weight cache

  const int T   = seqlen[0];
  const int g   = blockIdx.x;
  const int tid = threadIdx.x;
  const int w   = tid >> 6;       // wave 0..15
  const int l   = tid & 63;
  const int l15 = l & 15;
  const int lq  = l >> 4;
  const int u   = w*16 + l15;     // hidden unit owned by this lane

  float bv[4];
  #pragma unroll
  for (int ga = 0; ga < 4; ++ga) bv[ga] = bias[ga*256 + u];

  // Register weight cache: kt 0-3 of each gate (16 frags = 64 VGPR), PINNED:
  // the asm makes each value opaque so the compiler cannot rematerialize the
  // loads inside the loop (which is what silently happened at VGPR_Count=64).
  bf16x8 wregs[4][4];   // [kt][ga]
  #pragma unroll
  for (int kc = 0; kc < 4; ++kc)
    #pragma unroll
    for (int ga = 0; ga < 4; ++ga)
      wregs[kc][ga] = *(const bf16x8*)(Wsum_p + (size_t)((ga*16 + w)*8 + kc)*512 + l*8);
  #pragma unroll
  for (int kc = 0; kc < 4; ++kc)
    #pragma unroll
    for (int ga = 0; ga < 4; ++ga)
      asm volatile("" : "+v"(wregs[kc][ga]));

  // LDS weight cache: 9 frags/wave (kt4 ga0-3, kt5 ga0-3, kt6 ga0), loaded once
  #pragma unroll
  for (int idx = 0; idx < 9; ++idx){
    const int kt = (idx < 8) ? (4 + (idx >> 2)) : 6;
    const int ga = (idx < 8) ? (idx & 3) : 0;
    *(bf16x8*)&wl[((w*9) + idx)*512 + l*8] =
      *(const bf16x8*)(Wsum_p + (size_t)((ga*16 + w)*8 + kt)*512 + l*8);
  }

  // Stage t=0 input (x = h_in) into hb[0], A-frag layout (same offsets as epilogue)
  {
    const int ktu = w >> 1;
    const int kgu = ((w & 1) << 1) | (l15 >> 3);
    const int ju  = l15 & 7;
    #pragma unroll
    for (int r = 0; r < 4; ++r){
      const int m = lq*4 + r;
      hb[ktu*512 + (kgu*16 + m)*8 + ju] = f2bf(h_in[(size_t)(g*BM + m)*HID + u]);
    }
  }

  float cs[4] = {0.f, 0.f, 0.f, 0.f};
  __syncthreads();

  lstm_step<true>(0, T, g, w, l, l15, lq, hb, hb + 4096, wl, wregs, Wih_p, Wsum_p, bv, cs, out);
  STEP_BARRIER();
  int buf = 1;
  for (int t = 1; t < T; ++t){
    lstm_step<false>(t, T, g, w, l, l15, lq,
                     hb + buf*4096, hb + (buf^1)*4096, wl, wregs, Wih_p, Wsum_p, bv, cs, out);
    STEP_BARRIER();
    buf ^= 1;
  }
}

extern "C" void kernel_launch(void* const* d_in, const int* in_sizes, int n_in,
                              void* d_out, int out_size, void* d_ws, size_t ws_size,
                              hipStream_t stream) {
  const float* h_in = (const float*)d_in[0];
  const float* Wih  = (const float*)d_in[1];
  const float* Whh  = (const float*)d_in[2];
  const float* bih  = (const float*)d_in[3];
  const float* bhh  = (const float*)d_in[4];
  const int*   seq  = (const int*)  d_in[5];
  float* out = (float*)d_out;

  unsigned short* Wih_p  = (unsigned short*)d_ws;                    // 512 KB
  unsigned short* Wsum_p = Wih_p + (size_t)NGATE * HID;              // 512 KB
  float*          bias   = (float*)(Wsum_p + (size_t)NGATE * HID);   // 4 KB

  static bool attr_set = false;
  if (!attr_set){
    hipFuncSetAttribute((const void*)lstm_kernel,
                        hipFuncAttributeMaxDynamicSharedMemorySize, LDS_BYTES);
    attr_set = true;
  }

  pack_kernel<<<dim3((NGATE*HID)/256), dim3(256), 0, stream>>>(
      Wih, Whh, bih, bhh, Wih_p, Wsum_p, bias);

  lstm_kernel<<<dim3(NWG), dim3(TPB), LDS_BYTES, stream>>>(
      h_in, Wih_p, Wsum_p, bias, seq, out);
}

// Round 4
// 3386.827 us; speedup vs baseline: 1.0647x; 1.0647x over previous
//
#include <hip/hip_runtime.h>

#define HID   256
#define BATCH 2048
#define NGATE 1024
#define BM    16        // batch rows per workgroup
#define NWG   128       // BATCH/BM
#define TPB   512       // 8 waves -> 2 waves/SIMD -> 256 VGPR budget
#define LDS_BYTES 163840  // 16KB h double-buffer + 144KB weight cache (full 160KB LDS)

typedef __attribute__((ext_vector_type(8))) short bf16x8;
typedef __attribute__((ext_vector_type(4))) float f32x4;

__device__ __forceinline__ unsigned short f2bf(float x){
  unsigned int u = __builtin_bit_cast(unsigned int, x);
  u += 0x7fffu + ((u >> 16) & 1u);          // RNE
  return (unsigned short)(u >> 16);
}
__device__ __forceinline__ float fsigm(float x){
  return __builtin_amdgcn_rcpf(1.0f + __expf(-x));
}
__device__ __forceinline__ float ftanh_(float x){
  return fmaf(2.0f, __builtin_amdgcn_rcpf(1.0f + __expf(-2.0f*x)), -1.0f);
}

#define MFMA(a,b,c) __builtin_amdgcn_mfma_f32_16x16x32_bf16((a),(b),(c),0,0,0)

// lgkmcnt-only barrier: orders LDS hnext writes/reads without draining the
// global output stores (vmcnt) every step.
#define STEP_BARRIER() do {                                   \
    __builtin_amdgcn_sched_barrier(0);                        \
    asm volatile("s_waitcnt lgkmcnt(0)" ::: "memory");        \
    __builtin_amdgcn_s_barrier();                             \
    __builtin_amdgcn_sched_barrier(0);                        \
  } while (0)

// Pack W_ih and (W_ih+W_hh) into MFMA B-fragment order:
// frag(nt,kt) is 1024B, lane-linear: lane l holds W[nt*16 + (l&15)][kt*32 + (l>>4)*8 + j]
__global__ void pack_kernel(const float* __restrict__ Wih, const float* __restrict__ Whh,
                            const float* __restrict__ bih, const float* __restrict__ bhh,
                            unsigned short* __restrict__ Wih_p,
                            unsigned short* __restrict__ Wsum_p,
                            float* __restrict__ bias){
  int tid = blockIdx.x * blockDim.x + threadIdx.x;   // 0..262143
  int j  = tid & 7;
  int ln = (tid >> 3) & 63;
  int kt = (tid >> 9) & 7;
  int nt = tid >> 12;
  int n = nt*16 + (ln & 15);
  int k = kt*32 + (ln >> 4)*8 + j;
  float wih = Wih[n*HID + k];
  float whh = Whh[n*HID + k];
  Wih_p[tid]  = f2bf(wih);
  Wsum_p[tid] = f2bf(wih + whh);
  if (tid < NGATE) bias[tid] = bih[tid] + bhh[tid];
}

// Wave w owns hidden units [32w, 32w+32) = (ga, ut) output tiles nt = ga*16 + w*2 + ut.
// Per-wave B-frags: 64 total = 4 ga x 2 ut x 8 kt.
//   REG  (28): kt0-2 all (24) + kt3 ga0-1 (4)         -> 112 VGPR, asm-pinned
//   LDS  (18): kt3 ga2-3 (4) + kt4 all (8) + kt5 ga0-2 (6)   -> 18KB/wave, once
//   STRM (18): kt5 ga3 (2) + kt6 all (8) + kt7 all (8)       -> 18KB/wave/step from L2
__global__ __launch_bounds__(TPB, 2)
void lstm_kernel(const float* __restrict__ h_in,
                 const unsigned short* __restrict__ Wih_p,
                 const unsigned short* __restrict__ Wsum_p,
                 const float* __restrict__ bias,
                 const int* __restrict__ seqlen,
                 float* __restrict__ out){
  extern __shared__ unsigned short lds[];
  unsigned short* hb = lds;           // [2][4096] h in A-frag layout (double buffer)
  unsigned short* wl = lds + 8192;    // [8 waves][18 frags][512]

  const int T   = seqlen[0];
  const int g   = blockIdx.x;
  const int tid = threadIdx.x;
  const int w   = tid >> 6;       // wave 0..7
  const int l   = tid & 63;
  const int l15 = l & 15;
  const int lq  = l >> 4;

  // global ushort offset of B-frag (ga, ut, kt) for this wave/lane
  auto WOFF = [&](int ga, int ut, int kt) -> size_t {
    return ((size_t)((ga*16 + w*2 + ut)*8 + kt))*512 + (size_t)l*8;
  };

  float bv[4][2];
  #pragma unroll
  for (int ga = 0; ga < 4; ++ga)
    #pragma unroll
    for (int ut = 0; ut < 2; ++ut)
      bv[ga][ut] = bias[ga*256 + w*32 + ut*16 + l15];

  // ---- register weight cache: 28 frags (112 VGPR), pinned ----
  bf16x8 wr[28];
  #pragma unroll
  for (int kt = 0; kt < 3; ++kt)
    #pragma unroll
    for (int ga = 0; ga < 4; ++ga)
      #pragma unroll
      for (int ut = 0; ut < 2; ++ut)
        wr[kt*8 + ga*2 + ut] = *(const bf16x8*)(Wsum_p + WOFF(ga, ut, kt));
  #pragma unroll
  for (int ga = 0; ga < 2; ++ga)
    #pragma unroll
    for (int ut = 0; ut < 2; ++ut)
      wr[24 + ga*2 + ut] = *(const bf16x8*)(Wsum_p + WOFF(ga, ut, 3));
  #pragma unroll
  for (int i = 0; i < 28; ++i) asm volatile("" : "+v"(wr[i]));

  // ---- LDS weight cache: 18 frags/wave, loaded once ----
  // idx 0-3: kt3 ga2-3; idx 4-11: kt4; idx 12-17: kt5 ga0-2  (inner idx = ga*2+ut)
  #pragma unroll
  for (int ga = 2; ga < 4; ++ga)
    #pragma unroll
    for (int ut = 0; ut < 2; ++ut)
      *(bf16x8*)&wl[((w*18) + (ga-2)*2 + ut)*512 + l*8] =
        *(const bf16x8*)(Wsum_p + WOFF(ga, ut, 3));
  #pragma unroll
  for (int ga = 0; ga < 4; ++ga)
    #pragma unroll
    for (int ut = 0; ut < 2; ++ut)
      *(bf16x8*)&wl[((w*18) + 4 + ga*2 + ut)*512 + l*8] =
        *(const bf16x8*)(Wsum_p + WOFF(ga, ut, 4));
  #pragma unroll
  for (int ga = 0; ga < 3; ++ga)
    #pragma unroll
    for (int ut = 0; ut < 2; ++ut)
      *(bf16x8*)&wl[((w*18) + 12 + ga*2 + ut)*512 + l*8] =
        *(const bf16x8*)(Wsum_p + WOFF(ga, ut, 5));

  // ---- stage t=0 input (x = h_in) into hb[0], A-frag layout ----
  // unit u -> frag kt = u>>5 = w, kgroup = (u&31)>>3, j = u&7; row m = lq*4+r
  #pragma unroll
  for (int ut = 0; ut < 2; ++ut){
    const int u   = w*32 + ut*16 + l15;
    const int kgu = (u & 31) >> 3;
    const int ju  = u & 7;
    #pragma unroll
    for (int r = 0; r < 4; ++r){
      const int m = lq*4 + r;
      hb[w*512 + (kgu*16 + m)*8 + ju] = f2bf(h_in[(size_t)(g*BM + m)*HID + u]);
    }
  }

  float cs[2][4];
  #pragma unroll
  for (int ut = 0; ut < 2; ++ut)
    #pragma unroll
    for (int r = 0; r < 4; ++r) cs[ut][r] = 0.0f;

  __syncthreads();

  auto step = [&](int t, const unsigned short* __restrict__ hcur,
                  unsigned short* __restrict__ hnext, bool first){
    f32x4 acc[4][2];
    #pragma unroll
    for (int ga = 0; ga < 4; ++ga)
      #pragma unroll
      for (int ut = 0; ut < 2; ++ut){
        acc[ga][ut][0] = bv[ga][ut]; acc[ga][ut][1] = bv[ga][ut];
        acc[ga][ut][2] = bv[ga][ut]; acc[ga][ut][3] = bv[ga][ut];
      }

    if (first){
      // t==0 uses W_ih: stream everything, one time. Keep loop rolled to
      // bound register pressure (8 frags live max).
      #pragma unroll 1
      for (int kt = 0; kt < 8; ++kt){
        bf16x8 av = *(const bf16x8*)&hcur[kt*512 + l*8];
        #pragma unroll
        for (int ga = 0; ga < 4; ++ga)
          #pragma unroll
          for (int ut = 0; ut < 2; ++ut){
            bf16x8 bfr = *(const bf16x8*)(Wih_p + WOFF(ga, ut, kt));
            acc[ga][ut] = MFMA(av, bfr, acc[ga][ut]);
          }
      }
    } else {
      // batch A: kt5 ga3 (2) + kt6 ga0 (2) -> 16 VGPR in flight
      bf16x8 sA[4];
      sA[0] = *(const bf16x8*)(Wsum_p + WOFF(3, 0, 5));
      sA[1] = *(const bf16x8*)(Wsum_p + WOFF(3, 1, 5));
      sA[2] = *(const bf16x8*)(Wsum_p + WOFF(0, 0, 6));
      sA[3] = *(const bf16x8*)(Wsum_p + WOFF(0, 1, 6));
      __builtin_amdgcn_sched_barrier(0);

      // kt0-2: pinned register weights (24 MFMAs of load cover)
      #pragma unroll
      for (int kt = 0; kt < 3; ++kt){
        bf16x8 av = *(const bf16x8*)&hcur[kt*512 + l*8];
        #pragma unroll
        for (int ga = 0; ga < 4; ++ga)
          #pragma unroll
          for (int ut = 0; ut < 2; ++ut)
            acc[ga][ut] = MFMA(av, wr[kt*8 + ga*2 + ut], acc[ga][ut]);
      }

      // batch B: kt6 ga1-3 (6 frags, 24 VGPR)
      bf16x8 sB[6];
      #pragma unroll
      for (int ga = 1; ga < 4; ++ga)
        #pragma unroll
        for (int ut = 0; ut < 2; ++ut)
          sB[(ga-1)*2 + ut] = *(const bf16x8*)(Wsum_p + WOFF(ga, ut, 6));
      __builtin_amdgcn_sched_barrier(0);

      // kt3: reg ga0-1 + LDS ga2-3
      {
        bf16x8 av = *(const bf16x8*)&hcur[3*512 + l*8];
        #pragma unroll
        for (int ga = 0; ga < 2; ++ga)
          #pragma unroll
          for (int ut = 0; ut < 2; ++ut)
            acc[ga][ut] = MFMA(av, wr[24 + ga*2 + ut], acc[ga][ut]);
        #pragma unroll
        for (int ga = 2; ga < 4; ++ga)
          #pragma unroll
          for (int ut = 0; ut < 2; ++ut){
            bf16x8 bfr = *(const bf16x8*)&wl[((w*18) + (ga-2)*2 + ut)*512 + l*8];
            acc[ga][ut] = MFMA(av, bfr, acc[ga][ut]);
          }
      }
      // kt4: LDS
      {
        bf16x8 av = *(const bf16x8*)&hcur[4*512 + l*8];
        #pragma unroll
        for (int ga = 0; ga < 4; ++ga)
          #pragma unroll
          for (int ut = 0; ut < 2; ++ut){
            bf16x8 bfr = *(const bf16x8*)&wl[((w*18) + 4 + ga*2 + ut)*512 + l*8];
            acc[ga][ut] = MFMA(av, bfr, acc[ga][ut]);
          }
      }

      // batch C: kt7 all (8 frags, 32 VGPR)
      bf16x8 sC[8];
      #pragma unroll
      for (int ga = 0; ga < 4; ++ga)
        #pragma unroll
        for (int ut = 0; ut < 2; ++ut)
          sC[ga*2 + ut] = *(const bf16x8*)(Wsum_p + WOFF(ga, ut, 7));
      __builtin_amdgcn_sched_barrier(0);

      // kt5: LDS ga0-2 + stream ga3 (batch A)
      {
        bf16x8 av = *(const bf16x8*)&hcur[5*512 + l*8];
        #pragma unroll
        for (int ga = 0; ga < 3; ++ga)
          #pragma unroll
          for (int ut = 0; ut < 2; ++ut){
            bf16x8 bfr = *(const bf16x8*)&wl[((w*18) + 12 + ga*2 + ut)*512 + l*8];
            acc[ga][ut] = MFMA(av, bfr, acc[ga][ut]);
          }
        acc[3][0] = MFMA(av, sA[0], acc[3][0]);
        acc[3][1] = MFMA(av, sA[1], acc[3][1]);
      }
      // kt6: batch A ga0 + batch B ga1-3
      {
        bf16x8 av = *(const bf16x8*)&hcur[6*512 + l*8];
        acc[0][0] = MFMA(av, sA[2], acc[0][0]);
        acc[0][1] = MFMA(av, sA[3], acc[0][1]);
        #pragma unroll
        for (int ga = 1; ga < 4; ++ga)
          #pragma unroll
          for (int ut = 0; ut < 2; ++ut)
            acc[ga][ut] = MFMA(av, sB[(ga-1)*2 + ut], acc[ga][ut]);
      }
      // kt7: batch C
      {
        bf16x8 av = *(const bf16x8*)&hcur[7*512 + l*8];
        #pragma unroll
        for (int ga = 0; ga < 4; ++ga)
          #pragma unroll
          for (int ut = 0; ut < 2; ++ut)
            acc[ga][ut] = MFMA(av, sC[ga*2 + ut], acc[ga][ut]);
      }
    }

    // Epilogue: C layout col = l15 (unit), row = lq*4 + r. All gates in-lane.
    const int orow = first ? 0 : (T - t);        // x_hat[0]=h_0, x_hat[T-t]=h_t
    float* __restrict__ orp = out + (size_t)orow * (BATCH*HID);
    const bool last = (t == T - 1);

    #pragma unroll
    for (int ut = 0; ut < 2; ++ut){
      const int u   = w*32 + ut*16 + l15;
      const int kgu = (u & 31) >> 3;
      const int ju  = u & 7;
      #pragma unroll
      for (int r = 0; r < 4; ++r){
        const int m = lq*4 + r;
        const float iv = fsigm (acc[0][ut][r]);
        const float fv = fsigm (acc[1][ut][r]);
        const float gv = ftanh_(acc[2][ut][r]);
        const float ov = fsigm (acc[3][ut][r]);
        const float cn = fv * cs[ut][r] + iv * gv;
        cs[ut][r] = cn;
        const float hv = ov * ftanh_(cn);
        hnext[w*512 + (kgu*16 + m)*8 + ju] = f2bf(hv);
        const size_t gi = (size_t)(g*BM + m)*HID + u;
        orp[gi] = hv;
        if (last){
          out[(size_t)T*(BATCH*HID) + gi]       = hv;   // hf
          out[(size_t)(T + 1)*(BATCH*HID) + gi] = cn;   // cf
        }
      }
    }
  };

  step(0, hb, hb + 4096, true);
  STEP_BARRIER();
  int buf = 1;
  #pragma unroll 1
  for (int t = 1; t < T; ++t){
    step(t, hb + buf*4096, hb + (buf^1)*4096, false);
    STEP_BARRIER();
    buf ^= 1;
  }
}

extern "C" void kernel_launch(void* const* d_in, const int* in_sizes, int n_in,
                              void* d_out, int out_size, void* d_ws, size_t ws_size,
                              hipStream_t stream) {
  const float* h_in = (const float*)d_in[0];
  const float* Wih  = (const float*)d_in[1];
  const float* Whh  = (const float*)d_in[2];
  const float* bih  = (const float*)d_in[3];
  const float* bhh  = (const float*)d_in[4];
  const int*   seq  = (const int*)  d_in[5];
  float* out = (float*)d_out;

  unsigned short* Wih_p  = (unsigned short*)d_ws;                    // 512 KB
  unsigned short* Wsum_p = Wih_p + (size_t)NGATE * HID;              // 512 KB
  float*          bias   = (float*)(Wsum_p + (size_t)NGATE * HID);   // 4 KB

  static bool attr_set = false;
  if (!attr_set){
    hipFuncSetAttribute((const void*)lstm_kernel,
                        hipFuncAttributeMaxDynamicSharedMemorySize, LDS_BYTES);
    attr_set = true;
  }

  pack_kernel<<<dim3((NGATE*HID)/256), dim3(256), 0, stream>>>(
      Wih, Whh, bih, bhh, Wih_p, Wsum_p, bias);

  lstm_kernel<<<dim3(NWG), dim3(TPB), LDS_BYTES, stream>>>(
      h_in, Wih_p, Wsum_p, bias, seq, out);
}

// Round 5
// 3247.453 us; speedup vs baseline: 1.1104x; 1.0429x over previous
//
#include <hip/hip_runtime.h>

#define HID   256
#define BATCH 2048
#define NGATE 1024
#define BM    16        // batch rows per workgroup
#define NWG   128       // BATCH/BM
#define TPB   512       // 8 waves -> 2 waves/SIMD (LDS-forced 1 WG/CU)
#define LDS_BYTES 163840  // 16KB h double-buffer + 144KB weight cache (full 160KB LDS)

typedef __attribute__((ext_vector_type(8))) short bf16x8;
typedef __attribute__((ext_vector_type(4))) float f32x4;

__device__ __forceinline__ unsigned short f2bf(float x){
  unsigned int u = __builtin_bit_cast(unsigned int, x);
  u += 0x7fffu + ((u >> 16) & 1u);          // RNE
  return (unsigned short)(u >> 16);
}
__device__ __forceinline__ float fsigm(float x){
  return __builtin_amdgcn_rcpf(1.0f + __expf(-x));
}
__device__ __forceinline__ float ftanh_(float x){
  return fmaf(2.0f, __builtin_amdgcn_rcpf(1.0f + __expf(-2.0f*x)), -1.0f);
}

#define MFMA(a,b,c) __builtin_amdgcn_mfma_f32_16x16x32_bf16((a),(b),(c),0,0,0)

// lgkmcnt-only barrier: orders LDS hnext writes/reads without draining the
// global output stores (vmcnt) every step.
#define STEP_BARRIER() do {                                   \
    __builtin_amdgcn_sched_barrier(0);                        \
    asm volatile("s_waitcnt lgkmcnt(0)" ::: "memory");        \
    __builtin_amdgcn_s_barrier();                             \
    __builtin_amdgcn_sched_barrier(0);                        \
  } while (0)

// Pack W_ih and (W_ih+W_hh) into MFMA B-fragment order:
// frag(nt,kt) is 1024B, lane-linear: lane l holds W[nt*16 + (l&15)][kt*32 + (l>>4)*8 + j]
__global__ void pack_kernel(const float* __restrict__ Wih, const float* __restrict__ Whh,
                            const float* __restrict__ bih, const float* __restrict__ bhh,
                            unsigned short* __restrict__ Wih_p,
                            unsigned short* __restrict__ Wsum_p,
                            float* __restrict__ bias){
  int tid = blockIdx.x * blockDim.x + threadIdx.x;   // 0..262143
  int j  = tid & 7;
  int ln = (tid >> 3) & 63;
  int kt = (tid >> 9) & 7;
  int nt = tid >> 12;
  int n = nt*16 + (ln & 15);
  int k = kt*32 + (ln >> 4)*8 + j;
  float wih = Wih[n*HID + k];
  float whh = Whh[n*HID + k];
  Wih_p[tid]  = f2bf(wih);
  Wsum_p[tid] = f2bf(wih + whh);
  if (tid < NGATE) bias[tid] = bih[tid] + bhh[tid];
}

// Wave w owns hidden units [32w, 32w+32) = (ga, ut) output tiles nt = ga*16 + w*2 + ut.
// Per-wave B-frags: 64 total = 4 ga x 2 ut x 8 kt.
//   REG  (40): kt0-4 all gates/ut          -> 160 VGPR, asm-pinned (budget is REAL
//              this time: amdgpu_waves_per_eu(2,2) => 256 VGPR/wave)
//   LDS  (18): kt5 all (8) + kt6 all (8) + kt7 ga0 (2)   -> 18KB/wave, loaded once
//   STRM  (6): kt7 ga1-3                   -> 6KB/wave/step from L2, issued at top
__global__ __attribute__((amdgpu_flat_work_group_size(TPB, TPB), amdgpu_waves_per_eu(2, 2)))
void lstm_kernel(const float* __restrict__ h_in,
                 const unsigned short* __restrict__ Wih_p,
                 const unsigned short* __restrict__ Wsum_p,
                 const float* __restrict__ bias,
                 const int* __restrict__ seqlen,
                 float* __restrict__ out){
  extern __shared__ unsigned short lds[];
  unsigned short* hb = lds;           // [2][4096] h in A-frag layout (double buffer)
  unsigned short* wl = lds + 8192;    // [8 waves][18 frags][512]

  const int T   = seqlen[0];
  const int g   = blockIdx.x;
  const int tid = threadIdx.x;
  const int w   = tid >> 6;       // wave 0..7
  const int l   = tid & 63;
  const int l15 = l & 15;
  const int lq  = l >> 4;

  // global ushort offset of B-frag (ga, ut, kt) for this wave/lane
  auto WOFF = [&](int ga, int ut, int kt) -> size_t {
    return ((size_t)((ga*16 + w*2 + ut)*8 + kt))*512 + (size_t)l*8;
  };

  float bv[4][2];
  #pragma unroll
  for (int ga = 0; ga < 4; ++ga)
    #pragma unroll
    for (int ut = 0; ut < 2; ++ut)
      bv[ga][ut] = bias[ga*256 + w*32 + ut*16 + l15];

  // ---- register weight cache: 40 frags (160 VGPR), pinned ----
  bf16x8 wr[40];
  #pragma unroll
  for (int kt = 0; kt < 5; ++kt)
    #pragma unroll
    for (int ga = 0; ga < 4; ++ga)
      #pragma unroll
      for (int ut = 0; ut < 2; ++ut)
        wr[kt*8 + ga*2 + ut] = *(const bf16x8*)(Wsum_p + WOFF(ga, ut, kt));
  #pragma unroll
  for (int i = 0; i < 40; ++i) asm volatile("" : "+v"(wr[i]));

  // ---- LDS weight cache: 18 frags/wave, loaded once ----
  // idx 0-7: kt5 (ga*2+ut); idx 8-15: kt6; idx 16-17: kt7 ga0 (ut)
  #pragma unroll
  for (int ga = 0; ga < 4; ++ga)
    #pragma unroll
    for (int ut = 0; ut < 2; ++ut){
      *(bf16x8*)&wl[((w*18) + ga*2 + ut)*512 + l*8] =
        *(const bf16x8*)(Wsum_p + WOFF(ga, ut, 5));
      *(bf16x8*)&wl[((w*18) + 8 + ga*2 + ut)*512 + l*8] =
        *(const bf16x8*)(Wsum_p + WOFF(ga, ut, 6));
    }
  #pragma unroll
  for (int ut = 0; ut < 2; ++ut)
    *(bf16x8*)&wl[((w*18) + 16 + ut)*512 + l*8] =
      *(const bf16x8*)(Wsum_p + WOFF(0, ut, 7));

  // ---- stage t=0 input (x = h_in) into hb[0], A-frag layout ----
  #pragma unroll
  for (int ut = 0; ut < 2; ++ut){
    const int u   = w*32 + ut*16 + l15;
    const int kgu = (u & 31) >> 3;
    const int ju  = u & 7;
    #pragma unroll
    for (int r = 0; r < 4; ++r){
      const int m = lq*4 + r;
      hb[w*512 + (kgu*16 + m)*8 + ju] = f2bf(h_in[(size_t)(g*BM + m)*HID + u]);
    }
  }

  float cs[2][4];
  #pragma unroll
  for (int ut = 0; ut < 2; ++ut)
    #pragma unroll
    for (int r = 0; r < 4; ++r) cs[ut][r] = 0.0f;

  __syncthreads();

  auto step = [&](int t, const unsigned short* __restrict__ hcur,
                  unsigned short* __restrict__ hnext, bool first){
    f32x4 acc[4][2];
    #pragma unroll
    for (int ga = 0; ga < 4; ++ga)
      #pragma unroll
      for (int ut = 0; ut < 2; ++ut){
        acc[ga][ut][0] = bv[ga][ut]; acc[ga][ut][1] = bv[ga][ut];
        acc[ga][ut][2] = bv[ga][ut]; acc[ga][ut][3] = bv[ga][ut];
      }

    if (first){
      // t==0 uses W_ih: stream everything, one time. Keep loop rolled to
      // bound register pressure (8 frags live max).
      #pragma unroll 1
      for (int kt = 0; kt < 8; ++kt){
        bf16x8 av = *(const bf16x8*)&hcur[kt*512 + l*8];
        #pragma unroll
        for (int ga = 0; ga < 4; ++ga)
          #pragma unroll
          for (int ut = 0; ut < 2; ++ut){
            bf16x8 bfr = *(const bf16x8*)(Wih_p + WOFF(ga, ut, kt));
            acc[ga][ut] = MFMA(av, bfr, acc[ga][ut]);
          }
      }
    } else {
      // S1: the only streamed frags (kt7 ga1-3, 6 frags = 24 VGPR), issued at
      // the very top, consumed at the very end (kt7) -> ~50 MFMAs of cover.
      bf16x8 s1[6];
      #pragma unroll
      for (int ga = 1; ga < 4; ++ga)
        #pragma unroll
        for (int ut = 0; ut < 2; ++ut)
          s1[(ga-1)*2 + ut] = *(const bf16x8*)(Wsum_p + WOFF(ga, ut, 7));
      __builtin_amdgcn_sched_barrier(0);

      // kt0-4: pinned register weights (40 MFMAs, no B memory dependence)
      #pragma unroll
      for (int kt = 0; kt < 5; ++kt){
        bf16x8 av = *(const bf16x8*)&hcur[kt*512 + l*8];
        #pragma unroll
        for (int ga = 0; ga < 4; ++ga)
          #pragma unroll
          for (int ut = 0; ut < 2; ++ut)
            acc[ga][ut] = MFMA(av, wr[kt*8 + ga*2 + ut], acc[ga][ut]);
      }

      // kt5: LDS (idx 0-7)
      {
        bf16x8 av = *(const bf16x8*)&hcur[5*512 + l*8];
        #pragma unroll
        for (int ga = 0; ga < 4; ++ga)
          #pragma unroll
          for (int ut = 0; ut < 2; ++ut){
            bf16x8 bfr = *(const bf16x8*)&wl[((w*18) + ga*2 + ut)*512 + l*8];
            acc[ga][ut] = MFMA(av, bfr, acc[ga][ut]);
          }
      }
      // kt6: LDS (idx 8-15)
      {
        bf16x8 av = *(const bf16x8*)&hcur[6*512 + l*8];
        #pragma unroll
        for (int ga = 0; ga < 4; ++ga)
          #pragma unroll
          for (int ut = 0; ut < 2; ++ut){
            bf16x8 bfr = *(const bf16x8*)&wl[((w*18) + 8 + ga*2 + ut)*512 + l*8];
            acc[ga][ut] = MFMA(av, bfr, acc[ga][ut]);
          }
      }
      // kt7: ga0 from LDS (idx 16-17), ga1-3 from stream
      {
        bf16x8 av = *(const bf16x8*)&hcur[7*512 + l*8];
        #pragma unroll
        for (int ut = 0; ut < 2; ++ut){
          bf16x8 b0 = *(const bf16x8*)&wl[((w*18) + 16 + ut)*512 + l*8];
          acc[0][ut] = MFMA(av, b0, acc[0][ut]);
        }
        #pragma unroll
        for (int ga = 1; ga < 4; ++ga)
          #pragma unroll
          for (int ut = 0; ut < 2; ++ut)
            acc[ga][ut] = MFMA(av, s1[(ga-1)*2 + ut], acc[ga][ut]);
      }
    }

    // Epilogue: C layout col = l15 (unit), row = lq*4 + r. All gates in-lane.
    const int orow = first ? 0 : (T - t);        // x_hat[0]=h_0, x_hat[T-t]=h_t
    float* __restrict__ orp = out + (size_t)orow * (BATCH*HID);
    const bool last = (t == T - 1);

    #pragma unroll
    for (int ut = 0; ut < 2; ++ut){
      const int u   = w*32 + ut*16 + l15;
      const int kgu = (u & 31) >> 3;
      const int ju  = u & 7;
      #pragma unroll
      for (int r = 0; r < 4; ++r){
        const int m = lq*4 + r;
        const float iv = fsigm (acc[0][ut][r]);
        const float fv = fsigm (acc[1][ut][r]);
        const float gv = ftanh_(acc[2][ut][r]);
        const float ov = fsigm (acc[3][ut][r]);
        const float cn = fv * cs[ut][r] + iv * gv;
        cs[ut][r] = cn;
        const float hv = ov * ftanh_(cn);
        hnext[w*512 + (kgu*16 + m)*8 + ju] = f2bf(hv);
        const size_t gi = (size_t)(g*BM + m)*HID + u;
        orp[gi] = hv;
        if (last){
          out[(size_t)T*(BATCH*HID) + gi]       = hv;   // hf
          out[(size_t)(T + 1)*(BATCH*HID) + gi] = cn;   // cf
        }
      }
    }
  };

  step(0, hb, hb + 4096, true);
  STEP_BARRIER();
  int buf = 1;
  #pragma unroll 1
  for (int t = 1; t < T; ++t){
    step(t, hb + buf*4096, hb + (buf^1)*4096, false);
    STEP_BARRIER();
    buf ^= 1;
  }
}

extern "C" void kernel_launch(void* const* d_in, const int* in_sizes, int n_in,
                              void* d_out, int out_size, void* d_ws, size_t ws_size,
                              hipStream_t stream) {
  const float* h_in = (const float*)d_in[0];
  const float* Wih  = (const float*)d_in[1];
  const float* Whh  = (const float*)d_in[2];
  const float* bih  = (const float*)d_in[3];
  const float* bhh  = (const float*)d_in[4];
  const int*   seq  = (const int*)  d_in[5];
  float* out = (float*)d_out;

  unsigned short* Wih_p  = (unsigned short*)d_ws;                    // 512 KB
  unsigned short* Wsum_p = Wih_p + (size_t)NGATE * HID;              // 512 KB
  float*          bias   = (float*)(Wsum_p + (size_t)NGATE * HID);   // 4 KB

  static bool attr_set = false;
  if (!attr_set){
    hipFuncSetAttribute((const void*)lstm_kernel,
                        hipFuncAttributeMaxDynamicSharedMemorySize, LDS_BYTES);
    attr_set = true;
  }

  pack_kernel<<<dim3((NGATE*HID)/256), dim3(256), 0, stream>>>(
      Wih, Whh, bih, bhh, Wih_p, Wsum_p, bias);

  lstm_kernel<<<dim3(NWG), dim3(TPB), LDS_BYTES, stream>>>(
      h_in, Wih_p, Wsum_p, bias, seq, out);
}